// Round 3
// baseline (617.155 us; speedup 1.0000x reference)
//
#include <hip/hip_runtime.h>
#include <math.h>

#define CEPS 1e-9f

typedef _Float16 half8 __attribute__((ext_vector_type(8)));
typedef float floatx16 __attribute__((ext_vector_type(16)));

// x  : [4,56,56,8,32] fp32    W: [4,4,128,32] fp32    bias: [128] fp32
// out: [4,112,112,128] fp32 act
//
// votes[b'][pix][m=(pixl,i)][ca] = sum_{tap,ci} xf[...]*W[kh][kw][ca][ci]
// xf[b'][h][w][i][ci] = x[i&3][h][w][2b'+(i>>2)][ci]   (reference reshape scramble)
// Wave = M32 (4 pixels along v x 8 i), N=128 (4 tiles), K=128 (8 steps of 16).
// Block = 4 waves = 4x4 pixel tile, one parity class (rh,rw), one b'.
// W is pre-converted to f16 B-fragment order in d_ws (per parity) by prep_w.

// sum over the 16-lane DPP row (a-group) via rotate-reduce: pure VALU, no LDS pipe
__device__ __forceinline__ float row_sum16(float v) {
    v += __int_as_float(__builtin_amdgcn_update_dpp(0, __float_as_int(v), 0x128, 0xF, 0xF, false)); // ror:8
    v += __int_as_float(__builtin_amdgcn_update_dpp(0, __float_as_int(v), 0x124, 0xF, 0xF, false)); // ror:4
    v += __int_as_float(__builtin_amdgcn_update_dpp(0, __float_as_int(v), 0x122, 0xF, 0xF, false)); // ror:2
    v += __int_as_float(__builtin_amdgcn_update_dpp(0, __float_as_int(v), 0x121, 0xF, 0xF, false)); // ror:1
    return v;
}

// B[k][n] fragment table: idx = ((parity*8 + s)*4 + t)*64 + l -> 8 f16
__global__ __launch_bounds__(256) void prep_w(const float* __restrict__ Wt,
                                              _Float16* __restrict__ wb) {
    int idx = blockIdx.x * 256 + threadIdx.x;    // [0, 8192)
    int parity = idx >> 11;
    int s = (idx >> 8) & 7;
    int t = (idx >> 6) & 3;
    int l = idx & 63;
    int rh = parity >> 1, rw = parity & 1;
    int n = t * 32 + (l & 31);
    int h = l >> 5;
    int ci0 = ((s & 1) << 4) + (h << 3);
    int kh = ((s >> 2) << 1) + 1 - rh;
    int kw = (((s >> 1) & 1) << 1) + 1 - rw;
    const float* src = Wt + (((kh * 4 + kw) * 128 + n) << 5) + ci0;
    float4 w0 = *(const float4*)src;
    float4 w1 = *(const float4*)(src + 4);
    half8 hv;
    hv[0] = (_Float16)w0.x; hv[1] = (_Float16)w0.y;
    hv[2] = (_Float16)w0.z; hv[3] = (_Float16)w0.w;
    hv[4] = (_Float16)w1.x; hv[5] = (_Float16)w1.y;
    hv[6] = (_Float16)w1.z; hv[7] = (_Float16)w1.w;
    *(half8*)(wb + ((long)idx << 3)) = hv;
}

__global__ __launch_bounds__(256, 6) void caps_mfma(
    const float* __restrict__ x,
    const _Float16* __restrict__ wb,
    const float* __restrict__ bias,
    float* __restrict__ out)
{
    // x tile: [cell(5x5)][i(8)][ci padded 32->40] f16
    __shared__ _Float16 xt[25 * 8 * 40];       // 16000 B

    const int tid = threadIdx.x;
    const int tile = blockIdx.x;            // 0..195 : 14x14 tiles of 4x4 pixels
    const int tu = tile / 14, tv = tile - tu * 14;
    const int u0 = tu * 4, v0 = tv * 4;
    const int rh = blockIdx.y >> 1;         // p & 1
    const int rw = blockIdx.y & 1;          // q & 1
    const int bp = blockIdx.z;              // b'
    const _Float16* wsrc = wb + ((long)blockIdx.y << 14);   // parity slice, 16K f16

    // ---- stage x: fp32 -> f16 tile [ri(5)][rj(5)][i(8)][ci], zero-filled OOB ----
    #pragma unroll
    for (int it = 0; it < 4; ++it) {
        int idx = tid + (it << 8);
        if (idx < 800) {
            int cell = idx >> 5;            // 0..24
            int r = idx & 31;
            int i = r >> 2;
            int ci0 = (r & 3) << 3;
            int ri = cell / 5, rj = cell - ri * 5;
            int gi = u0 + rh - 1 + ri;
            int gj = v0 + rw - 1 + rj;
            float tmp[8] = {0.f, 0.f, 0.f, 0.f, 0.f, 0.f, 0.f, 0.f};
            if ((unsigned)gi < 56u && (unsigned)gj < 56u) {
                const float* src = x + (((i & 3) * 56 + gi) * 56 + gj) * 256
                                     + ((bp * 2 + (i >> 2)) << 5) + ci0;
                float4 a0 = *(const float4*)src;
                float4 a1 = *(const float4*)(src + 4);
                tmp[0] = a0.x; tmp[1] = a0.y; tmp[2] = a0.z; tmp[3] = a0.w;
                tmp[4] = a1.x; tmp[5] = a1.y; tmp[6] = a1.z; tmp[7] = a1.w;
            }
            half8 hv;
            #pragma unroll
            for (int j = 0; j < 8; ++j) hv[j] = (_Float16)tmp[j];
            *(half8*)(xt + (cell * 8 + i) * 40 + ci0) = hv;
        }
    }
    __syncthreads();

    const int l = tid & 63;
    const int w = tid >> 6;                 // wave = u-row within tile
    const int pixA = (l >> 3) & 3;
    const int iA = l & 7;
    const int hA = l >> 5;
    const int invA = (pixA * 8 + iA) * 40 + (hA << 3);

    floatx16 acc[4];
    #pragma unroll
    for (int t = 0; t < 4; ++t)
        #pragma unroll
        for (int j = 0; j < 16; ++j) acc[t][j] = 0.f;

    // ---- MFMA K-loop: 8 k-steps x 4 n-tiles; B-frags straight from global (L1/L2) ----
    #pragma unroll
    for (int s = 0; s < 8; ++s) {
        const int tkh = s >> 2;
        const int tkw = (s >> 1) & 1;
        const int row = w + 1 - tkh;
        const int aoff = (row * 5 + 1 - tkw) * 320 + ((s & 1) << 4) + invA;
        half8 af = *(const half8*)(xt + aoff);
        #pragma unroll
        for (int t = 0; t < 4; ++t) {
            half8 bf = *(const half8*)(wsrc + (((s * 4 + t) * 64 + l) << 3));
            acc[t] = __builtin_amdgcn_mfma_f32_32x32x16_f16(af, bf, acc[t], 0, 0, 0);
        }
    }

    // ---- routing, in-register. C-layout: pix=reg>>2, i=(reg&3)+4*(l>>5), ca=t*32+(l&31) ----
    // a = l&15 (DPP row), c = t*2 + ((l>>4)&1)
    float bs[4];
    #pragma unroll
    for (int t = 0; t < 4; ++t) bs[t] = bias[t * 32 + (l & 31)];

    #pragma unroll
    for (int pixl = 0; pixl < 4; ++pixl) {
        float v[4][4];                       // [il][t]
        #pragma unroll
        for (int il = 0; il < 4; ++il)
            #pragma unroll
            for (int t = 0; t < 4; ++t) v[il][t] = acc[t][pixl * 4 + il];

        float lg[4][4];
        float pre[4], act_[4];

        // ---- round 0: uniform route = 1/8 ----
        #pragma unroll
        for (int t = 0; t < 4; ++t) {
            float s4 = (v[0][t] + v[1][t]) + (v[2][t] + v[3][t]);
            s4 += __shfl_xor(s4, 32);
            pre[t] = fmaf(0.125f, s4, bs[t]);
        }
        #pragma unroll
        for (int t = 0; t < 4; ++t) {
            float nq = row_sum16(pre[t] * pre[t]);
            float sc = nq * __builtin_amdgcn_rcpf(1.f + nq)
                          * __builtin_amdgcn_rsqf(nq + CEPS);
            act_[t] = pre[t] * sc;
        }
        #pragma unroll
        for (int il = 0; il < 4; ++il)
            #pragma unroll
            for (int t = 0; t < 4; ++t)
                lg[il][t] = row_sum16(v[il][t] * act_[t]);

        // ---- rounds 1,2 ----
        #pragma unroll
        for (int r = 1; r < 3; ++r) {
            float route[4][4];
            #pragma unroll
            for (int il = 0; il < 4; ++il) {
                // softmax over 8 c (4 in-lane t + xor16); logits bounded (~±3), no max-sub
                float e0 = __expf(lg[il][0]);
                float e1 = __expf(lg[il][1]);
                float e2 = __expf(lg[il][2]);
                float e3 = __expf(lg[il][3]);
                float ss = (e0 + e1) + (e2 + e3);
                ss += __shfl_xor(ss, 16);
                float rs = __builtin_amdgcn_rcpf(ss);
                route[il][0] = e0 * rs; route[il][1] = e1 * rs;
                route[il][2] = e2 * rs; route[il][3] = e3 * rs;
            }
            #pragma unroll
            for (int t = 0; t < 4; ++t) {
                float p = 0.f;
                #pragma unroll
                for (int il = 0; il < 4; ++il) p = fmaf(route[il][t], v[il][t], p);
                p += __shfl_xor(p, 32);
                pre[t] = p + bs[t];
            }
            #pragma unroll
            for (int t = 0; t < 4; ++t) {
                float nq = row_sum16(pre[t] * pre[t]);
                float sc = nq * __builtin_amdgcn_rcpf(1.f + nq)
                              * __builtin_amdgcn_rsqf(nq + CEPS);
                act_[t] = pre[t] * sc;
            }
            if (r < 2) {
                #pragma unroll
                for (int il = 0; il < 4; ++il)
                    #pragma unroll
                    for (int t = 0; t < 4; ++t)
                        lg[il][t] += row_sum16(v[il][t] * act_[t]);
            }
        }

        const int p = ((u0 + w) << 1) + rh;
        const int q = ((v0 + pixl) << 1) + rw;
        float* op = out + (((bp * 112 + p) * 112 + q) << 7) + (l & 31);
        #pragma unroll
        for (int t = 0; t < 4; ++t) op[t << 5] = act_[t];
    }
}

extern "C" void kernel_launch(void* const* d_in, const int* in_sizes, int n_in,
                              void* d_out, int out_size, void* d_ws, size_t ws_size,
                              hipStream_t stream) {
    const float* x  = (const float*)d_in[0];
    const float* Wt = (const float*)d_in[1];
    const float* b  = (const float*)d_in[2];
    float* out = (float*)d_out;
    _Float16* wb = (_Float16*)d_ws;          // 4 parities x 16384 f16 = 64 KB

    prep_w<<<32, 256, 0, stream>>>(Wt, wb);
    dim3 grid(196, 4, 4);    // 14x14 4x4-pixel tiles, 4 parity classes, 4 b'
    caps_mfma<<<grid, 256, 0, stream>>>(x, wb, b, out);
}

// Round 4
// 139.085 us; speedup vs baseline: 4.4372x; 4.4372x over previous
//
#include <hip/hip_runtime.h>
#include <math.h>

#define CEPS 1e-9f

typedef _Float16 half8 __attribute__((ext_vector_type(8)));
typedef float floatx16 __attribute__((ext_vector_type(16)));

// x  : [4,56,56,8,32] fp32    W: [4,4,128,32] fp32    bias: [128] fp32
// out: [4,112,112,128] fp32 act
//
// votes[b'][pix][m=(pixl,i)][ca] = sum_{tap,ci} xf[...]*W[kh][kw][ca][ci]
// xf[b'][h][w][i][ci] = x[i&3][h][w][2b'+(i>>2)][ci]   (reference reshape scramble)
// Wave = M32 (4 pixels along v x 8 i), N=128 (4 tiles), K=128 (8 steps of 16).
// Block = 4 waves = 4x4 pixel tile, one parity class (rh,rw), one b'.
// W is pre-converted to f16 B-fragment order in d_ws (per parity) by prep_w.
//
// NOTE: launch_bounds min-waves MUST stay <=4: acc[4] = 64 accumulator regs share
// the unified VGPR file; bound 6 capped VGPRs at 80 and spilled 2.1 GB to scratch (R3).

// sum over the 16-lane DPP row (a-group) via rotate-reduce: pure VALU, no LDS pipe
__device__ __forceinline__ float row_sum16(float v) {
    v += __int_as_float(__builtin_amdgcn_update_dpp(0, __float_as_int(v), 0x128, 0xF, 0xF, false)); // ror:8
    v += __int_as_float(__builtin_amdgcn_update_dpp(0, __float_as_int(v), 0x124, 0xF, 0xF, false)); // ror:4
    v += __int_as_float(__builtin_amdgcn_update_dpp(0, __float_as_int(v), 0x122, 0xF, 0xF, false)); // ror:2
    v += __int_as_float(__builtin_amdgcn_update_dpp(0, __float_as_int(v), 0x121, 0xF, 0xF, false)); // ror:1
    return v;
}

// B[k][n] fragment table: idx = ((parity*8 + s)*4 + t)*64 + l -> 8 f16
__global__ __launch_bounds__(256) void prep_w(const float* __restrict__ Wt,
                                              _Float16* __restrict__ wb) {
    int idx = blockIdx.x * 256 + threadIdx.x;    // [0, 8192)
    int parity = idx >> 11;
    int s = (idx >> 8) & 7;
    int t = (idx >> 6) & 3;
    int l = idx & 63;
    int rh = parity >> 1, rw = parity & 1;
    int n = t * 32 + (l & 31);
    int h = l >> 5;
    int ci0 = ((s & 1) << 4) + (h << 3);
    int kh = ((s >> 2) << 1) + 1 - rh;
    int kw = (((s >> 1) & 1) << 1) + 1 - rw;
    const float* src = Wt + (((kh * 4 + kw) * 128 + n) << 5) + ci0;
    float4 w0 = *(const float4*)src;
    float4 w1 = *(const float4*)(src + 4);
    half8 hv;
    hv[0] = (_Float16)w0.x; hv[1] = (_Float16)w0.y;
    hv[2] = (_Float16)w0.z; hv[3] = (_Float16)w0.w;
    hv[4] = (_Float16)w1.x; hv[5] = (_Float16)w1.y;
    hv[6] = (_Float16)w1.z; hv[7] = (_Float16)w1.w;
    *(half8*)(wb + ((long)idx << 3)) = hv;
}

__global__ __launch_bounds__(256, 4) void caps_mfma(
    const float* __restrict__ x,
    const _Float16* __restrict__ wb,
    const float* __restrict__ bias,
    float* __restrict__ out)
{
    // x tile: [cell(5x5)][i(8)][ci padded 32->40] f16
    __shared__ _Float16 xt[25 * 8 * 40];       // 16000 B

    const int tid = threadIdx.x;
    const int tile = blockIdx.x;            // 0..195 : 14x14 tiles of 4x4 pixels
    const int tu = tile / 14, tv = tile - tu * 14;
    const int u0 = tu * 4, v0 = tv * 4;
    const int rh = blockIdx.y >> 1;         // p & 1
    const int rw = blockIdx.y & 1;          // q & 1
    const int bp = blockIdx.z;              // b'
    const _Float16* wsrc = wb + ((long)blockIdx.y << 14);   // parity slice, 16K f16

    // ---- stage x: fp32 -> f16 tile [ri(5)][rj(5)][i(8)][ci], zero-filled OOB ----
    #pragma unroll
    for (int it = 0; it < 4; ++it) {
        int idx = tid + (it << 8);
        if (idx < 800) {
            int cell = idx >> 5;            // 0..24
            int r = idx & 31;
            int i = r >> 2;
            int ci0 = (r & 3) << 3;
            int ri = cell / 5, rj = cell - ri * 5;
            int gi = u0 + rh - 1 + ri;
            int gj = v0 + rw - 1 + rj;
            float tmp[8] = {0.f, 0.f, 0.f, 0.f, 0.f, 0.f, 0.f, 0.f};
            if ((unsigned)gi < 56u && (unsigned)gj < 56u) {
                const float* src = x + (((i & 3) * 56 + gi) * 56 + gj) * 256
                                     + ((bp * 2 + (i >> 2)) << 5) + ci0;
                float4 a0 = *(const float4*)src;
                float4 a1 = *(const float4*)(src + 4);
                tmp[0] = a0.x; tmp[1] = a0.y; tmp[2] = a0.z; tmp[3] = a0.w;
                tmp[4] = a1.x; tmp[5] = a1.y; tmp[6] = a1.z; tmp[7] = a1.w;
            }
            half8 hv;
            #pragma unroll
            for (int j = 0; j < 8; ++j) hv[j] = (_Float16)tmp[j];
            *(half8*)(xt + (cell * 8 + i) * 40 + ci0) = hv;
        }
    }
    __syncthreads();

    const int l = tid & 63;
    const int w = tid >> 6;                 // wave = u-row within tile
    const int pixA = (l >> 3) & 3;
    const int iA = l & 7;
    const int hA = l >> 5;
    const int invA = (pixA * 8 + iA) * 40 + (hA << 3);

    floatx16 acc[4];
    #pragma unroll
    for (int t = 0; t < 4; ++t)
        #pragma unroll
        for (int j = 0; j < 16; ++j) acc[t][j] = 0.f;

    // ---- MFMA K-loop: 8 k-steps x 4 n-tiles; B-frags straight from global (L1/L2) ----
    #pragma unroll
    for (int s = 0; s < 8; ++s) {
        const int tkh = s >> 2;
        const int tkw = (s >> 1) & 1;
        const int row = w + 1 - tkh;
        const int aoff = (row * 5 + 1 - tkw) * 320 + ((s & 1) << 4) + invA;
        half8 af = *(const half8*)(xt + aoff);
        #pragma unroll
        for (int t = 0; t < 4; ++t) {
            half8 bf = *(const half8*)(wsrc + (((s * 4 + t) * 64 + l) << 3));
            acc[t] = __builtin_amdgcn_mfma_f32_32x32x16_f16(af, bf, acc[t], 0, 0, 0);
        }
    }

    // ---- routing, in-register. C-layout: pix=reg>>2, i=(reg&3)+4*(l>>5), ca=t*32+(l&31) ----
    // a = l&15 (DPP row), c = t*2 + ((l>>4)&1)
    float bs[4];
    #pragma unroll
    for (int t = 0; t < 4; ++t) bs[t] = bias[t * 32 + (l & 31)];

    #pragma unroll
    for (int pixl = 0; pixl < 4; ++pixl) {
        float v[4][4];                       // [il][t]
        #pragma unroll
        for (int il = 0; il < 4; ++il)
            #pragma unroll
            for (int t = 0; t < 4; ++t) v[il][t] = acc[t][pixl * 4 + il];

        float lg[4][4];
        float pre[4], act_[4];

        // ---- round 0: uniform route = 1/8 ----
        #pragma unroll
        for (int t = 0; t < 4; ++t) {
            float s4 = (v[0][t] + v[1][t]) + (v[2][t] + v[3][t]);
            s4 += __shfl_xor(s4, 32);
            pre[t] = fmaf(0.125f, s4, bs[t]);
        }
        #pragma unroll
        for (int t = 0; t < 4; ++t) {
            float nq = row_sum16(pre[t] * pre[t]);
            float sc = nq * __builtin_amdgcn_rcpf(1.f + nq)
                          * __builtin_amdgcn_rsqf(nq + CEPS);
            act_[t] = pre[t] * sc;
        }
        #pragma unroll
        for (int il = 0; il < 4; ++il)
            #pragma unroll
            for (int t = 0; t < 4; ++t)
                lg[il][t] = row_sum16(v[il][t] * act_[t]);

        // ---- rounds 1,2 ----
        #pragma unroll
        for (int r = 1; r < 3; ++r) {
            float route[4][4];
            #pragma unroll
            for (int il = 0; il < 4; ++il) {
                // softmax over 8 c (4 in-lane t + xor16); logits bounded (~±3), no max-sub
                float e0 = __expf(lg[il][0]);
                float e1 = __expf(lg[il][1]);
                float e2 = __expf(lg[il][2]);
                float e3 = __expf(lg[il][3]);
                float ss = (e0 + e1) + (e2 + e3);
                ss += __shfl_xor(ss, 16);
                float rs = __builtin_amdgcn_rcpf(ss);
                route[il][0] = e0 * rs; route[il][1] = e1 * rs;
                route[il][2] = e2 * rs; route[il][3] = e3 * rs;
            }
            #pragma unroll
            for (int t = 0; t < 4; ++t) {
                float p = 0.f;
                #pragma unroll
                for (int il = 0; il < 4; ++il) p = fmaf(route[il][t], v[il][t], p);
                p += __shfl_xor(p, 32);
                pre[t] = p + bs[t];
            }
            #pragma unroll
            for (int t = 0; t < 4; ++t) {
                float nq = row_sum16(pre[t] * pre[t]);
                float sc = nq * __builtin_amdgcn_rcpf(1.f + nq)
                              * __builtin_amdgcn_rsqf(nq + CEPS);
                act_[t] = pre[t] * sc;
            }
            if (r < 2) {
                #pragma unroll
                for (int il = 0; il < 4; ++il)
                    #pragma unroll
                    for (int t = 0; t < 4; ++t)
                        lg[il][t] += row_sum16(v[il][t] * act_[t]);
            }
        }

        const int p = ((u0 + w) << 1) + rh;
        const int q = ((v0 + pixl) << 1) + rw;
        float* op = out + (((bp * 112 + p) * 112 + q) << 7) + (l & 31);
        #pragma unroll
        for (int t = 0; t < 4; ++t) op[t << 5] = act_[t];
    }
}

extern "C" void kernel_launch(void* const* d_in, const int* in_sizes, int n_in,
                              void* d_out, int out_size, void* d_ws, size_t ws_size,
                              hipStream_t stream) {
    const float* x  = (const float*)d_in[0];
    const float* Wt = (const float*)d_in[1];
    const float* b  = (const float*)d_in[2];
    float* out = (float*)d_out;
    _Float16* wb = (_Float16*)d_ws;          // 4 parities x 16384 f16 = 64 KB

    prep_w<<<32, 256, 0, stream>>>(Wt, wb);
    dim3 grid(196, 4, 4);    // 14x14 4x4-pixel tiles, 4 parity classes, 4 b'
    caps_mfma<<<grid, 256, 0, stream>>>(x, wb, b, out);
}